// Round 1
// baseline (23361.778 us; speedup 1.0000x reference)
//
#include <hip/hip_runtime.h>
#include <cstdint>
#include <cstddef>

#define T_STEPS 256
#define BATCH   32
#define VOCABSZ 32000
#define EMBSZ   512
#define HIDSZ   1024
#define NB      128     // persistent blocks for LSTM (must all be co-resident; 128 <= 256 CUs)
#define NTHR    512     // 8 waves

typedef __attribute__((ext_vector_type(8)))  short          short8;
typedef __attribute__((ext_vector_type(4)))  float          f32x4;
typedef __attribute__((ext_vector_type(16))) float          f32x16;
typedef __attribute__((ext_vector_type(4)))  unsigned short ushort4v;

__device__ __forceinline__ unsigned short f32_to_bf16(float f) {
  unsigned u = __builtin_bit_cast(unsigned, f);
  u += 0x7fffu + ((u >> 16) & 1u);
  return (unsigned short)(u >> 16);
}

__device__ __forceinline__ float sigmoidf_(float x) { return 1.f / (1.f + expf(-x)); }

// ---------------- embedding gather -> bf16 [8192][512] ----------------
__global__ void gather_embed(const int* __restrict__ data,
                             const float* __restrict__ emb,
                             unsigned short* __restrict__ xout) {
  int row = blockIdx.x;                 // t*32 + b
  int v = data[row];
  const f32x4* src = (const f32x4*)(emb + (size_t)v * EMBSZ);
  f32x4 f = src[threadIdx.x];           // 128 threads * 4 floats = 512
  ushort4v o;
  o.x = f32_to_bf16(f.x); o.y = f32_to_bf16(f.y);
  o.z = f32_to_bf16(f.z); o.w = f32_to_bf16(f.w);
  ((ushort4v*)(xout + (size_t)row * EMBSZ))[threadIdx.x] = o;
}

// ------------- transpose-convert: in f32 [R][C] -> out bf16 [C][R] -------------
__global__ void transpose_to_bf16(const float* __restrict__ in,
                                  unsigned short* __restrict__ out,
                                  int R, int C) {
  __shared__ float tile[32][33];
  int c0 = blockIdx.x * 32, r0 = blockIdx.y * 32;
  int tx = threadIdx.x & 31, ty = threadIdx.x >> 5;     // 256 threads
  for (int r = ty; r < 32; r += 8)
    tile[r][tx] = in[(size_t)(r0 + r) * C + c0 + tx];
  __syncthreads();
  for (int r = ty; r < 32; r += 8)
    out[(size_t)(c0 + r) * R + r0 + tx] = f32_to_bf16(tile[tx][r]);
}

// ---------------- persistent LSTM layer ----------------
// xin  : [T][32][Din] bf16
// Wt   : [4096][K] bf16 (transposed weights, K = Din+1024); col order: [i|g|f|o] x 1024 units
// yout : [T][32][1024] bf16
// hbuf : [2][32][1024] bf16 (double buffer)
__global__ void __launch_bounds__(NTHR, 2)
lstm_layer(const unsigned short* __restrict__ xin,
           const unsigned short* __restrict__ Wt,
           const float* __restrict__ bias,
           unsigned short* __restrict__ yout,
           unsigned short* __restrict__ hbuf,
           unsigned int* __restrict__ counter,
           int Din)
{
  __shared__ float gl[8 * 32 * 33];     // per-wave partial gates [8][32 batch][33]
  const int K    = Din + HIDSZ;
  const int Ks16 = K >> 4;              // 16-wide k-steps total (96 or 128)
  const int Ks8  = Ks16 >> 3;           // per-wave k-steps (12 or 16)
  const int xs16 = Din >> 4;            // k-steps belonging to x part

  const int tid  = threadIdx.x;
  const int w    = tid >> 6;
  const int lane = tid & 63;
  const int blk  = blockIdx.x;
  const int m    = lane & 31;           // batch row (A operand, m = lane&31)
  const int kgrp = (lane >> 5) << 3;    // 0 or 8 (k sub-offset within 16)
  const int nloc = lane & 31;           // local col 0..31 (B/C operand col)

  const int kb = w * Ks8;               // this wave's k-range start
  // local col -> global W column: gate = nloc>>3, unit = blk*8 + (nloc&7)
  const int gcol = ((nloc >> 3) * HIDSZ) + (blk << 3) + (nloc & 7);

  // preload this wave's B fragments into registers (<=16 x short8 = 64 VGPR)
  short8 breg[16];
  const unsigned short* wbase = Wt + (size_t)gcol * K + kgrp;
#pragma unroll
  for (int r = 0; r < 16; ++r)
    if (r < Ks8) breg[r] = *(const short8*)(wbase + ((kb + r) << 4));

  int nkx = xs16 - kb;                  // t==0: only x part of K
  if (nkx < 0) nkx = 0;
  if (nkx > Ks8) nkx = Ks8;

  // elementwise lane mapping (first 256 threads): unit eu (0..7), batch eb (0..31)
  const int eb = tid >> 3, eu = tid & 7;
  const int ucol = (blk << 3) + eu;
  float bi = 0.f, bg = 0.f, bff = 0.f, bo = 0.f, cst = 0.f;
  if (tid < 256) {
    bi  = bias[ucol];
    bg  = bias[HIDSZ + ucol];
    bff = bias[2 * HIDSZ + ucol] + 1.0f;   // hk.LSTM forget bias +1
    bo  = bias[3 * HIDSZ + ucol];
  }

  for (int t = 0; t < T_STEPS; ++t) {
    const int nk = (t == 0) ? nkx : Ks8;
    const unsigned short* xrow = xin + ((size_t)t * BATCH + m) * Din + kgrp;
    const unsigned short* hrow = hbuf + ((t & 1) * (BATCH * HIDSZ)) + m * HIDSZ + kgrp;

    f32x16 acc0, acc1;
#pragma unroll
    for (int i = 0; i < 16; ++i) { acc0[i] = 0.f; acc1[i] = 0.f; }

#pragma unroll
    for (int r = 0; r < 16; r += 2) {
      if (r < nk) {
        int ks = kb + r;
        const unsigned short* a = (ks < xs16) ? (xrow + (ks << 4))
                                              : (hrow + ((ks - xs16) << 4));
        acc0 = __builtin_amdgcn_mfma_f32_32x32x16_bf16(*(const short8*)a, breg[r], acc0, 0, 0, 0);
      }
      if (r + 1 < nk) {
        int ks = kb + r + 1;
        const unsigned short* a = (ks < xs16) ? (xrow + (ks << 4))
                                              : (hrow + ((ks - xs16) << 4));
        acc1 = __builtin_amdgcn_mfma_f32_32x32x16_bf16(*(const short8*)a, breg[r + 1], acc1, 0, 0, 0);
      }
    }

    // write this wave's partial gates: C/D layout col=lane&31, row=(r&3)+8*(r>>2)+4*(lane>>5)
#pragma unroll
    for (int r = 0; r < 16; ++r) {
      int row = (r & 3) + ((r >> 2) << 3) + ((lane >> 5) << 2);
      gl[(w * 32 + row) * 33 + nloc] = acc0[r] + acc1[r];
    }
    __syncthreads();

    if (tid < 256) {
      float gi = bi, gg = bg, gf = bff, go = bo;
#pragma unroll
      for (int ww = 0; ww < 8; ++ww) {
        const float* gp = &gl[(ww * 32 + eb) * 33];
        gi += gp[eu]; gg += gp[8 + eu]; gf += gp[16 + eu]; go += gp[24 + eu];
      }
      float ig = sigmoidf_(gi);
      float gv = tanhf(gg);
      float fg = sigmoidf_(gf);
      float og = sigmoidf_(go);
      cst = fg * cst + ig * gv;
      float h = og * tanhf(cst);
      unsigned short hb = f32_to_bf16(h);
      hbuf[(((t + 1) & 1) * (BATCH * HIDSZ)) + eb * HIDSZ + ucol] = hb;
      yout[((size_t)t * BATCH + eb) * HIDSZ + ucol] = hb;
    }

    if (t < T_STEPS - 1) {
      // inter-block barrier: release h, arrive, spin, acquire
      __builtin_amdgcn_fence(__ATOMIC_RELEASE, "agent");
      __syncthreads();
      if (tid == 0) {
        __hip_atomic_fetch_add(counter, 1u, __ATOMIC_RELAXED, __HIP_MEMORY_SCOPE_AGENT);
        unsigned tgt = (unsigned)NB * (unsigned)(t + 1);
        while (__hip_atomic_load(counter, __ATOMIC_RELAXED, __HIP_MEMORY_SCOPE_AGENT) < tgt)
          __builtin_amdgcn_s_sleep(2);
      }
      __syncthreads();
      __builtin_amdgcn_fence(__ATOMIC_ACQUIRE, "agent");
    }
  }
}

// ---------------- decoder GEMM: C[8192][32000] = A[8192][1024] * Bt[32000][1024]^T + bias ----
__device__ __forceinline__ void stage16(const unsigned short* g, unsigned short* l) {
  __builtin_amdgcn_global_load_lds((const __attribute__((address_space(1))) unsigned int*)g,
                                   (__attribute__((address_space(3))) unsigned int*)l,
                                   16, 0, 0);
}

#define GRPN 10
__global__ void __launch_bounds__(256)
decoder_gemm(const unsigned short* __restrict__ A,
             const unsigned short* __restrict__ Bt,
             const float* __restrict__ bias,
             float* __restrict__ C)
{
  __shared__ unsigned short Al[128 * 32];
  __shared__ unsigned short Bl[128 * 32];
  int bid = blockIdx.x;
  int group = bid / (64 * GRPN);
  int rr = bid - group * (64 * GRPN);
  int bm = rr / GRPN;
  int bn = group * GRPN + (rr - (rr / GRPN) * GRPN);

  int tid = threadIdx.x;
  int wv = tid >> 6, lane = tid & 63;
  int wm = (wv & 1) << 6, wn = (wv >> 1) << 6;
  int fr = lane & 15, kg = (lane >> 4) << 3;

  const unsigned short* Ab = A + (size_t)(bm * 128) * 1024;
  const unsigned short* Bb = Bt + (size_t)(bn * 128) * 1024;
  int ra0 = tid >> 2,          ka0 = (tid & 3) << 3;
  int ra1 = (tid + 256) >> 2,  ka1 = ((tid + 256) & 3) << 3;

  f32x4 acc[16];
#pragma unroll
  for (int i = 0; i < 16; ++i) { acc[i].x = 0.f; acc[i].y = 0.f; acc[i].z = 0.f; acc[i].w = 0.f; }

  for (int kt = 0; kt < 32; ++kt) {
    int k0 = kt << 5;
    stage16(Ab + (size_t)ra0 * 1024 + k0 + ka0, Al + (size_t)tid * 8);
    stage16(Ab + (size_t)ra1 * 1024 + k0 + ka1, Al + (size_t)(tid + 256) * 8);
    stage16(Bb + (size_t)ra0 * 1024 + k0 + ka0, Bl + (size_t)tid * 8);
    stage16(Bb + (size_t)ra1 * 1024 + k0 + ka1, Bl + (size_t)(tid + 256) * 8);
    __syncthreads();
    short8 av[4], bv[4];
#pragma unroll
    for (int i = 0; i < 4; ++i) av[i] = *(const short8*)&Al[(wm + (i << 4) + fr) * 32 + kg];
#pragma unroll
    for (int j = 0; j < 4; ++j) bv[j] = *(const short8*)&Bl[(wn + (j << 4) + fr) * 32 + kg];
#pragma unroll
    for (int i = 0; i < 4; ++i)
#pragma unroll
      for (int j = 0; j < 4; ++j)
        acc[i * 4 + j] = __builtin_amdgcn_mfma_f32_16x16x32_bf16(av[i], bv[j], acc[i * 4 + j], 0, 0, 0);
    __syncthreads();
  }

  float bj[4];
#pragma unroll
  for (int j = 0; j < 4; ++j) bj[j] = bias[bn * 128 + wn + (j << 4) + fr];
  int rq = (lane >> 4) << 2;
#pragma unroll
  for (int i = 0; i < 4; ++i) {
    int row = bm * 128 + wm + (i << 4) + rq;
    float* cp0 = C + (size_t)row * VOCABSZ + bn * 128 + wn + fr;
#pragma unroll
    for (int j = 0; j < 4; ++j) {
      float* cp = cp0 + (j << 4);
      f32x4 v = acc[i * 4 + j];
      cp[0]                     = v.x + bj[j];
      cp[(size_t)VOCABSZ]       = v.y + bj[j];
      cp[(size_t)2 * VOCABSZ]   = v.z + bj[j];
      cp[(size_t)3 * VOCABSZ]   = v.w + bj[j];
    }
  }
}

// ---------------- launcher ----------------
extern "C" void kernel_launch(void* const* d_in, const int* in_sizes, int n_in,
                              void* d_out, int out_size, void* d_ws, size_t ws_size,
                              hipStream_t stream) {
  const int*   data = (const int*)d_in[0];
  const float* emb  = (const float*)d_in[2];
  const float* W0   = (const float*)d_in[3];
  const float* b0   = (const float*)d_in[4];
  const float* W1   = (const float*)d_in[5];
  const float* b1   = (const float*)d_in[6];
  const float* W2   = (const float*)d_in[7];
  const float* b2   = (const float*)d_in[8];
  const float* Wd   = (const float*)d_in[9];
  const float* bd   = (const float*)d_in[10];
  float* out = (float*)d_out;

  char* p = (char*)d_ws;
  auto carve = [&](size_t bytes) {
    char* q = p; p += (bytes + 255) & ~(size_t)255; return q;
  };
  unsigned short* Wt0  = (unsigned short*)carve((size_t)4096 * 1536 * 2);
  unsigned short* Wt1  = (unsigned short*)carve((size_t)4096 * 2048 * 2);
  unsigned short* Wt2  = (unsigned short*)carve((size_t)4096 * 2048 * 2);
  unsigned short* Wdt  = (unsigned short*)carve((size_t)32000 * 1024 * 2);
  unsigned short* xemb = (unsigned short*)carve((size_t)8192 * 512 * 2);
  unsigned short* yA   = (unsigned short*)carve((size_t)8192 * 1024 * 2);
  unsigned short* yB   = (unsigned short*)carve((size_t)8192 * 1024 * 2);
  unsigned short* hbuf = (unsigned short*)carve((size_t)2 * 32 * 1024 * 2);
  unsigned int*   ctr  = (unsigned int*)carve(256);

  hipMemsetAsync(ctr, 0, 256, stream);
  gather_embed<<<8192, 128, 0, stream>>>(data, emb, xemb);
  transpose_to_bf16<<<dim3(4096 / 32, 1536 / 32), 256, 0, stream>>>(W0, Wt0, 1536, 4096);
  transpose_to_bf16<<<dim3(4096 / 32, 2048 / 32), 256, 0, stream>>>(W1, Wt1, 2048, 4096);
  transpose_to_bf16<<<dim3(4096 / 32, 2048 / 32), 256, 0, stream>>>(W2, Wt2, 2048, 4096);
  transpose_to_bf16<<<dim3(32000 / 32, 1024 / 32), 256, 0, stream>>>(Wd, Wdt, 1024, 32000);

  lstm_layer<<<NB, NTHR, 0, stream>>>(xemb, Wt0, b0, yA, hbuf, ctr + 0,  512);
  lstm_layer<<<NB, NTHR, 0, stream>>>(yA,   Wt1, b1, yB, hbuf, ctr + 16, 1024);
  lstm_layer<<<NB, NTHR, 0, stream>>>(yB,   Wt2, b2, yA, hbuf, ctr + 32, 1024);

  decoder_gemm<<<16000, 256, 0, stream>>>(yA, Wdt, bd, out);
}